// Round 1
// baseline (14006.578 us; speedup 1.0000x reference)
//
#include <hip/hip_runtime.h>

#define NLK 65536
#define LAY 4
#define NN (NLK * LAY)      // 262144 nodes
#define DYNF 32
#define STATF 8
#define GG 64
#define EUP 4194304
#define EIN 1048576
#define EFB 1048576

// norm table layout: [up: NN][inner: 4*NLK][fwd: 3*2NLK][bwd: 3*2NLK]
#define NORM_UP_OFF   0
#define NORM_IN_OFF   (NN)
#define NORM_F_OFF    (NN + 4 * NLK)
#define NORM_B_OFF    (NN + 4 * NLK + 6 * NLK)
#define NORM_TOT      (NN + 4 * NLK + 12 * NLK)   // 1,310,720

__global__ void fill_ones_kernel(int* deg, int n) {
    int i = blockIdx.x * blockDim.x + threadIdx.x;
    if (i < n) deg[i] = 1;   // self-loop baseline
}

__global__ void hist_kernel(const int* __restrict__ dst, int E, int* __restrict__ deg) {
    int i = blockIdx.x * blockDim.x + threadIdx.x;
    if (i < E) atomicAdd(&deg[dst[i]], 1);
}

__global__ void norm_kernel(const int* __restrict__ deg, float* __restrict__ norm, int n) {
    int i = blockIdx.x * blockDim.x + threadIdx.x;
    if (i < n) norm[i] = rsqrtf((float)deg[i]);
}

// h' = (in_rows ++ in_stat) @ W, then hs[r] = acc[r] = h'[r] * norm[r]
// (acc init = hs handles the self-loop term; norm[dst] applied at finalize)
template <int F1, bool HAS_STAT>
__global__ void mm_scale_kernel(const float* in_rows, const float* __restrict__ in_stat,
                                const float* __restrict__ W, const float* __restrict__ norm,
                                float* __restrict__ hs, float* acc, int nrows) {
    constexpr int FIN = F1 + (HAS_STAT ? STATF : 0);
    __shared__ float Ws[FIN * DYNF];
    for (int i = threadIdx.x; i < FIN * DYNF; i += blockDim.x) Ws[i] = W[i];
    __syncthreads();
    int r = blockIdx.x * blockDim.x + threadIdx.x;
    if (r >= nrows) return;
    float in[FIN];
    const float4* ip = (const float4*)(in_rows + (size_t)r * F1);
#pragma unroll
    for (int q = 0; q < F1 / 4; q++) {
        float4 v = ip[q];
        in[q * 4 + 0] = v.x; in[q * 4 + 1] = v.y; in[q * 4 + 2] = v.z; in[q * 4 + 3] = v.w;
    }
    if (HAS_STAT) {
        const float4* sp = (const float4*)(in_stat + (size_t)r * STATF);
#pragma unroll
        for (int q = 0; q < STATF / 4; q++) {
            float4 v = sp[q];
            in[F1 + q * 4 + 0] = v.x; in[F1 + q * 4 + 1] = v.y;
            in[F1 + q * 4 + 2] = v.z; in[F1 + q * 4 + 3] = v.w;
        }
    }
    float o[DYNF];
#pragma unroll
    for (int j = 0; j < DYNF; j++) o[j] = 0.f;
#pragma unroll
    for (int k = 0; k < FIN; k++) {
        float a = in[k];
#pragma unroll
        for (int j = 0; j < DYNF; j++) o[j] = fmaf(a, Ws[k * DYNF + j], o[j]);
    }
    float nm = norm[r];
    float4* hp = (float4*)(hs + (size_t)r * DYNF);
    float4* ap = (float4*)(acc + (size_t)r * DYNF);
#pragma unroll
    for (int q = 0; q < DYNF / 4; q++) {
        float4 v = make_float4(o[q * 4] * nm, o[q * 4 + 1] * nm, o[q * 4 + 2] * nm, o[q * 4 + 3] * nm);
        hp[q] = v;
        ap[q] = v;
    }
}

// 8 threads per edge, 4 floats each: acc[dst] += hs[src]
__global__ void edge_push_kernel(const int* __restrict__ esrc, const int* __restrict__ edst, int E,
                                 const float* __restrict__ hs, float* acc) {
    long tid = (long)blockIdx.x * blockDim.x + threadIdx.x;
    int e = (int)(tid >> 3);
    if (e >= E) return;
    int fq = ((int)tid & 7) * 4;
    int s = esrc[e];
    int d = edst[e];
    float4 v = *(const float4*)(hs + (size_t)s * DYNF + fq);
    float* a = acc + (size_t)d * DYNF + fq;
    unsafeAtomicAdd(a + 0, v.x);
    unsafeAtomicAdd(a + 1, v.y);
    unsafeAtomicAdd(a + 2, v.z);
    unsafeAtomicAdd(a + 3, v.w);
}

// out_h[r*32+j] = norm[row_lo+r]*acc[(row_lo+r)*32+j] + b[j]
__global__ void finalize_kernel(const float* __restrict__ acc, const float* __restrict__ norm,
                                const float* __restrict__ b, float* __restrict__ out_h,
                                int row_lo, int n_out) {
    int gidx = blockIdx.x * blockDim.x + threadIdx.x;
    if (gidx >= n_out * DYNF) return;
    int r = gidx >> 5;
    int j = gidx & 31;
    int lr = row_lo + r;
    out_h[gidx] = norm[lr] * acc[(size_t)lr * DYNF + j] + b[j];
}

__global__ void relu_kernel(float* h, int n) {
    int i = blockIdx.x * blockDim.x + threadIdx.x;
    if (i < n) h[i] = fmaxf(h[i], 0.f);
}

__global__ void init_out_kernel(float* out, const float* __restrict__ lin_b) {
    int i = threadIdx.x;
    if (i < GG) out[i] = lin_b[0];
}

// per-row dot with lin_W, LDS per-graph partials, one global atomic per (block, graph)
__global__ void pool_kernel(const float* __restrict__ h, const int* __restrict__ gids,
                            const float* __restrict__ linW, float* out) {
    __shared__ float part[GG];
    int t = threadIdx.x;
    if (t < GG) part[t] = 0.f;
    __syncthreads();
    int r = blockIdx.x * blockDim.x + t;
    float dotv = 0.f;
    const float4* hp = (const float4*)(h + (size_t)r * DYNF);
#pragma unroll
    for (int q = 0; q < 8; q++) {
        float4 v = hp[q];
        dotv += v.x * linW[q * 4 + 0] + v.y * linW[q * 4 + 1] +
                v.z * linW[q * 4 + 2] + v.w * linW[q * 4 + 3];
    }
    atomicAdd(&part[gids[r]], dotv);
    __syncthreads();
    if (t < GG) unsafeAtomicAdd(&out[t], part[t]);
}

static inline int cdiv(long a, int b) { return (int)((a + b - 1) / b); }

struct Ctx {
    hipStream_t st;
    float* hs;
    float* acc_fb;
};

static void run_conv(const Ctx& c, const float* in_rows, int F1, const float* in_stat,
                     const float* W, const float* b, const int* esrc, const int* edst, int E,
                     const float* norm, int nrows, float* acc,
                     float* out_h, int row_lo, int n_out) {
    if (F1 == 4)
        mm_scale_kernel<4, false><<<cdiv(nrows, 256), 256, 0, c.st>>>(in_rows, nullptr, W, norm, c.hs, acc, nrows);
    else
        mm_scale_kernel<32, true><<<cdiv(nrows, 256), 256, 0, c.st>>>(in_rows, in_stat, W, norm, c.hs, acc, nrows);
    edge_push_kernel<<<cdiv((long)E * 8, 256), 256, 0, c.st>>>(esrc, edst, E, c.hs, acc);
    finalize_kernel<<<cdiv((long)n_out * DYNF, 256), 256, 0, c.st>>>(acc, norm, b, out_h, row_lo, n_out);
}

extern "C" void kernel_launch(void* const* d_in, const int* in_sizes, int n_in,
                              void* d_out, int out_size, void* d_ws, size_t ws_size,
                              hipStream_t stream) {
    const float* x      = (const float*)d_in[0];
    const float* stat   = (const float*)d_in[1];
    const int*   e_up   = (const int*)d_in[2];
    const int*   e_in   = (const int*)d_in[3];
    const int*   e_f    = (const int*)d_in[4];
    const int*   e_b    = (const int*)d_in[5];
    const int*   gids   = (const int*)d_in[6];
    const float* W_up   = (const float*)d_in[7];
    const float* b_up   = (const float*)d_in[8];
    const float* W_in   = (const float*)d_in[9];
    const float* b_in   = (const float*)d_in[10];
    const float* W_f    = (const float*)d_in[11];
    const float* b_f    = (const float*)d_in[12];
    const float* W_b    = (const float*)d_in[13];
    const float* b_b    = (const float*)d_in[14];
    const float* lin_W  = (const float*)d_in[15];
    const float* lin_b  = (const float*)d_in[16];
    float* out = (float*)d_out;

    // workspace carve
    float* h      = (float*)d_ws;                       // NN*32
    float* hs     = h + (size_t)NN * DYNF;              // NN*32
    float* acc_fb = hs + (size_t)NN * DYNF;             // 2*NLK*32
    float* norms  = acc_fb + (size_t)2 * NLK * DYNF;    // NORM_TOT
    int*   deg    = (int*)(norms + NORM_TOT);           // NORM_TOT

    Ctx c{stream, hs, acc_fb};

    // ---- degree/norm tables (once per launch, reused across all 27 convs) ----
    fill_ones_kernel<<<cdiv(NORM_TOT, 256), 256, 0, stream>>>(deg, NORM_TOT);
    hist_kernel<<<cdiv(EUP, 256), 256, 0, stream>>>(e_up + EUP, EUP, deg + NORM_UP_OFF);
    for (int l = 0; l < 4; l++)
        hist_kernel<<<cdiv(EIN, 256), 256, 0, stream>>>(e_in + (size_t)(l * 2 + 1) * EIN, EIN,
                                                        deg + NORM_IN_OFF + l * NLK);
    for (int l = 0; l < 3; l++)
        hist_kernel<<<cdiv(EFB, 256), 256, 0, stream>>>(e_f + (size_t)(l * 2 + 1) * EFB, EFB,
                                                        deg + NORM_F_OFF + l * 2 * NLK);
    for (int l = 0; l < 3; l++)
        hist_kernel<<<cdiv(EFB, 256), 256, 0, stream>>>(e_b + (size_t)(l * 2 + 1) * EFB, EFB,
                                                        deg + NORM_B_OFF + l * 2 * NLK);
    norm_kernel<<<cdiv(NORM_TOT, 256), 256, 0, stream>>>(deg, norms, NORM_TOT);

    // ---- up conv: acc aliases h (writes all N rows) ----
    run_conv(c, x, 4, nullptr, W_up, b_up, e_up, e_up + EUP, EUP,
             norms + NORM_UP_OFF, NN, h, h, 0, NN);

    auto inner = [&](int l) {
        float* hsl = h + (size_t)l * NLK * DYNF;
        run_conv(c, hsl, 32, stat + (size_t)l * NLK * STATF, W_in, b_in,
                 e_in + (size_t)(l * 2) * EIN, e_in + (size_t)(l * 2 + 1) * EIN, EIN,
                 norms + NORM_IN_OFF + l * NLK, NLK, hsl, hsl, 0, NLK);
    };
    auto fwd = [&](int l) {
        run_conv(c, h + (size_t)l * NLK * DYNF, 32, stat + (size_t)l * NLK * STATF, W_f, b_f,
                 e_f + (size_t)(l * 2) * EFB, e_f + (size_t)(l * 2 + 1) * EFB, EFB,
                 norms + NORM_F_OFF + l * 2 * NLK, 2 * NLK, acc_fb,
                 h + (size_t)(l + 1) * NLK * DYNF, NLK, NLK);
    };
    auto bwd = [&](int lm1) {  // python l in {3,2,1} -> lm1 = l-1
        run_conv(c, h + (size_t)lm1 * NLK * DYNF, 32, stat + (size_t)lm1 * NLK * STATF, W_b, b_b,
                 e_b + (size_t)(lm1 * 2) * EFB, e_b + (size_t)(lm1 * 2 + 1) * EFB, EFB,
                 norms + NORM_B_OFF + lm1 * 2 * NLK, 2 * NLK, acc_fb,
                 h + (size_t)lm1 * NLK * DYNF, 0, NLK);
    };

    for (int p = 0; p < 2; p++) {
        for (int l = 0; l < 4; l++) {
            inner(l);
            if (l < 3) fwd(l);
        }
        relu_kernel<<<cdiv((long)NN * DYNF, 256), 256, 0, stream>>>(h, NN * DYNF);
        for (int l = 3; l >= 1; l--) {
            bwd(l - 1);
            inner(l - 1);
        }
        relu_kernel<<<cdiv((long)NN * DYNF, 256), 256, 0, stream>>>(h, NN * DYNF);
    }

    init_out_kernel<<<1, 64, 0, stream>>>(out, lin_b);
    pool_kernel<<<NN / 256, 256, 0, stream>>>(h, gids, lin_W, out);
}

// Round 2
// 2595.118 us; speedup vs baseline: 5.3973x; 5.3973x over previous
//
#include <hip/hip_runtime.h>

#define NLK 65536
#define NN (NLK * 4)        // 262144 nodes
#define DYNF 32
#define STATF 8
#define GG 64
#define EUP 4194304
#define EIN 1048576
#define EFB 1048576

// ---- per-list offsets --------------------------------------------------
// norm/cnt space: [up: NN][inner: 4*NLK][fwd: 3*2NLK][bwd: 3*2NLK]
#define NS_UP    0
#define NS_IN(l) (NN + (l) * NLK)
#define NS_F(l)  (NN + 4 * NLK + (l) * 2 * NLK)
#define NS_B(l)  (NN + 10 * NLK + (l) * 2 * NLK)
#define NS_TOT   (NN + 16 * NLK)                        // 1,310,720

// row_ptr space (each list gets n+1)
#define RP_UP    0
#define RP_IN(l) ((NN + 1) + (l) * (NLK + 1))
#define RP_F(l)  ((NN + 1) + 4 * (NLK + 1) + (l) * (2 * NLK + 1))
#define RP_B(l)  ((NN + 1) + 4 * (NLK + 1) + 3 * (2 * NLK + 1) + (l) * (2 * NLK + 1))
#define RP_TOT   ((NN + 1) + 4 * (NLK + 1) + 6 * (2 * NLK + 1))

// col space (sorted-by-dst src ids)
#define CO_UP    0
#define CO_IN(l) (EUP + (l) * EIN)
#define CO_F(l)  (EUP + 4 * EIN + (l) * EFB)
#define CO_B(l)  (EUP + 4 * EIN + 3 * EFB + (l) * EFB)
#define CO_TOT   (EUP + 4 * EIN + 6 * EFB)              // 14,680,064

static inline int cdiv(long a, int b) { return (int)((a + b - 1) / b); }

// ---- CSR build ---------------------------------------------------------

__global__ void fill_zero_kernel(int* p, int n) {
    int i = blockIdx.x * blockDim.x + threadIdx.x;
    if (i < n) p[i] = 0;
}

__global__ void hist_kernel(const int* __restrict__ dst, int E, int* __restrict__ cnt) {
    int i = blockIdx.x * blockDim.x + threadIdx.x;
    if (i < E) atomicAdd(&cnt[dst[i]], 1);
}

// norm = rsqrt(cnt + 1)  (self-loop)
__global__ void norm_kernel(const int* __restrict__ cnt, float* __restrict__ norm, int n) {
    int i = blockIdx.x * blockDim.x + threadIdx.x;
    if (i < n) norm[i] = rsqrtf((float)(cnt[i] + 1));
}

// block-local exclusive scan (1024/block); rp[i]=local excl, part[b]=block sum
__global__ void scan1_kernel(const int* __restrict__ cnt, int* __restrict__ rp,
                             int* __restrict__ part, int n) {
    __shared__ int sh[1024];
    int t = threadIdx.x;
    int i = blockIdx.x * 1024 + t;
    int v = (i < n) ? cnt[i] : 0;
    sh[t] = v;
    __syncthreads();
    for (int off = 1; off < 1024; off <<= 1) {
        int u = (t >= off) ? sh[t - off] : 0;
        __syncthreads();
        sh[t] += u;
        __syncthreads();
    }
    if (i < n) rp[i] = sh[t] - v;                 // exclusive
    if (t == 1023) part[blockIdx.x] = sh[1023];
}

// single block exclusive scan of part[m], m <= 256
__global__ void scan2_kernel(int* part, int m) {
    __shared__ int sh[256];
    int t = threadIdx.x;
    int v = (t < m) ? part[t] : 0;
    sh[t] = v;
    __syncthreads();
    for (int off = 1; off < 256; off <<= 1) {
        int u = (t >= off) ? sh[t - off] : 0;
        __syncthreads();
        sh[t] += u;
        __syncthreads();
    }
    if (t < m) part[t] = sh[t] - v;               // exclusive
}

__global__ void scan3_kernel(int* __restrict__ rp, const int* __restrict__ part, int n, int E) {
    int i = blockIdx.x * blockDim.x + threadIdx.x;
    if (i < n) rp[i] += part[i >> 10];
    if (i == 0) rp[n] = E;
}

// cur (= zeroed cnt) provides within-row slot; col[rp[d]+slot] = src
__global__ void scatter_kernel(const int* __restrict__ src, const int* __restrict__ dst, int E,
                               const int* __restrict__ rp, int* __restrict__ cur,
                               int* __restrict__ col) {
    int e = blockIdx.x * blockDim.x + threadIdx.x;
    if (e >= E) return;
    int d = dst[e];
    int pos = rp[d] + atomicAdd(&cur[d], 1);
    col[pos] = src[e];
}

// ---- conv --------------------------------------------------------------

// hs[r] = ((in_rows[r] ++ in_stat[r]) @ W) * norm[r]
template <int F1, bool HAS_STAT>
__global__ void mm_scale_kernel(const float* __restrict__ in_rows, const float* __restrict__ in_stat,
                                const float* __restrict__ W, const float* __restrict__ norm,
                                float* __restrict__ hs, int nrows) {
    constexpr int FIN = F1 + (HAS_STAT ? STATF : 0);
    __shared__ float Ws[FIN * DYNF];
    for (int i = threadIdx.x; i < FIN * DYNF; i += blockDim.x) Ws[i] = W[i];
    __syncthreads();
    int r = blockIdx.x * blockDim.x + threadIdx.x;
    if (r >= nrows) return;
    float in[FIN];
    const float4* ip = (const float4*)(in_rows + (size_t)r * F1);
#pragma unroll
    for (int q = 0; q < F1 / 4; q++) {
        float4 v = ip[q];
        in[q * 4 + 0] = v.x; in[q * 4 + 1] = v.y; in[q * 4 + 2] = v.z; in[q * 4 + 3] = v.w;
    }
    if (HAS_STAT) {
        const float4* sp = (const float4*)(in_stat + (size_t)r * STATF);
#pragma unroll
        for (int q = 0; q < STATF / 4; q++) {
            float4 v = sp[q];
            in[F1 + q * 4 + 0] = v.x; in[F1 + q * 4 + 1] = v.y;
            in[F1 + q * 4 + 2] = v.z; in[F1 + q * 4 + 3] = v.w;
        }
    }
    float o[DYNF];
#pragma unroll
    for (int j = 0; j < DYNF; j++) o[j] = 0.f;
#pragma unroll
    for (int k = 0; k < FIN; k++) {
        float a = in[k];
#pragma unroll
        for (int j = 0; j < DYNF; j++) o[j] = fmaf(a, Ws[k * DYNF + j], o[j]);
    }
    float nm = norm[r];
    float4* hp = (float4*)(hs + (size_t)r * DYNF);
#pragma unroll
    for (int q = 0; q < DYNF / 4; q++)
        hp[q] = make_float4(o[q * 4] * nm, o[q * 4 + 1] * nm, o[q * 4 + 2] * nm, o[q * 4 + 3] * nm);
}

// pull: out[r] = norm[r]*(hs[r] + sum_{e in row r} hs[col[e]]) + b
// 8 threads per dst row, float4 each. Indices r, col[] are window-local.
__global__ void pull_kernel(const int* __restrict__ rp, const int* __restrict__ col,
                            const float* __restrict__ hs, const float* __restrict__ nrm,
                            const float* __restrict__ b, float* __restrict__ out,
                            int row_lo, int n_rows) {
    int tid = blockIdx.x * blockDim.x + threadIdx.x;
    int rr = tid >> 3;
    if (rr >= n_rows) return;
    int r = row_lo + rr;
    int q = (tid & 7) * 4;
    int e0 = rp[r], e1 = rp[r + 1];
    float4 acc = *(const float4*)(hs + (size_t)r * DYNF + q);   // self-loop
    for (int e = e0; e < e1; e++) {
        int s = col[e];
        float4 v = *(const float4*)(hs + (size_t)s * DYNF + q);
        acc.x += v.x; acc.y += v.y; acc.z += v.z; acc.w += v.w;
    }
    float nm = nrm[r];
    float4 bv = *(const float4*)(b + q);
    *(float4*)(out + (size_t)r * DYNF + q) =
        make_float4(fmaf(acc.x, nm, bv.x), fmaf(acc.y, nm, bv.y),
                    fmaf(acc.z, nm, bv.z), fmaf(acc.w, nm, bv.w));
}

__global__ void relu_kernel(float* h, int n) {
    int i = blockIdx.x * blockDim.x + threadIdx.x;
    if (i < n) h[i] = fmaxf(h[i], 0.f);
}

__global__ void init_out_kernel(float* out, const float* __restrict__ lin_b) {
    int i = threadIdx.x;
    if (i < GG) out[i] = lin_b[0];
}

__global__ void pool_kernel(const float* __restrict__ h, const int* __restrict__ gids,
                            const float* __restrict__ linW, float* out) {
    __shared__ float part[GG];
    int t = threadIdx.x;
    if (t < GG) part[t] = 0.f;
    __syncthreads();
    int r = blockIdx.x * blockDim.x + t;
    float dotv = 0.f;
    const float4* hp = (const float4*)(h + (size_t)r * DYNF);
#pragma unroll
    for (int q = 0; q < 8; q++) {
        float4 v = hp[q];
        dotv += v.x * linW[q * 4 + 0] + v.y * linW[q * 4 + 1] +
                v.z * linW[q * 4 + 2] + v.w * linW[q * 4 + 3];
    }
    atomicAdd(&part[gids[r]], dotv);
    __syncthreads();
    if (t < GG) unsafeAtomicAdd(&out[t], part[t]);
}

// ------------------------------------------------------------------------

extern "C" void kernel_launch(void* const* d_in, const int* in_sizes, int n_in,
                              void* d_out, int out_size, void* d_ws, size_t ws_size,
                              hipStream_t stream) {
    const float* x     = (const float*)d_in[0];
    const float* stat  = (const float*)d_in[1];
    const int*   e_up  = (const int*)d_in[2];
    const int*   e_in  = (const int*)d_in[3];
    const int*   e_f   = (const int*)d_in[4];
    const int*   e_b   = (const int*)d_in[5];
    const int*   gids  = (const int*)d_in[6];
    const float* W_up  = (const float*)d_in[7];
    const float* b_up  = (const float*)d_in[8];
    const float* W_in  = (const float*)d_in[9];
    const float* b_in  = (const float*)d_in[10];
    const float* W_f   = (const float*)d_in[11];
    const float* b_f   = (const float*)d_in[12];
    const float* W_b   = (const float*)d_in[13];
    const float* b_b   = (const float*)d_in[14];
    const float* lin_W = (const float*)d_in[15];
    const float* lin_b = (const float*)d_in[16];
    float* out = (float*)d_out;

    // workspace carve (~142 MB)
    float* h     = (float*)d_ws;                    // NN*32
    float* hs    = h + (size_t)NN * DYNF;           // NN*32
    float* norms = hs + (size_t)NN * DYNF;          // NS_TOT
    int*   cnt   = (int*)(norms + NS_TOT);          // NS_TOT
    int*   rp    = cnt + NS_TOT;                    // RP_TOT
    int*   col   = rp + RP_TOT;                     // CO_TOT
    int*   part  = col + CO_TOT;                    // 256

    // ---- describe the 11 distinct edge lists ----
    struct ListDesc { const int* src; const int* dst; int E; int n; int ns; int rpo; int co; };
    ListDesc LD[11];
    LD[0] = { e_up, e_up + EUP, EUP, NN, NS_UP, RP_UP, CO_UP };
    for (int l = 0; l < 4; l++)
        LD[1 + l] = { e_in + (size_t)(l * 2) * EIN, e_in + (size_t)(l * 2 + 1) * EIN,
                      EIN, NLK, NS_IN(l), RP_IN(l), CO_IN(l) };
    for (int l = 0; l < 3; l++)
        LD[5 + l] = { e_f + (size_t)(l * 2) * EFB, e_f + (size_t)(l * 2 + 1) * EFB,
                      EFB, 2 * NLK, NS_F(l), RP_F(l), CO_F(l) };
    for (int l = 0; l < 3; l++)
        LD[8 + l] = { e_b + (size_t)(l * 2) * EFB, e_b + (size_t)(l * 2 + 1) * EFB,
                      EFB, 2 * NLK, NS_B(l), RP_B(l), CO_B(l) };

    // ---- CSR build (once per launch, reused across all 27 convs) ----
    fill_zero_kernel<<<cdiv(NS_TOT, 256), 256, 0, stream>>>(cnt, NS_TOT);
    for (int i = 0; i < 11; i++)
        hist_kernel<<<cdiv(LD[i].E, 256), 256, 0, stream>>>(LD[i].dst, LD[i].E, cnt + LD[i].ns);
    norm_kernel<<<cdiv(NS_TOT, 256), 256, 0, stream>>>(cnt, norms, NS_TOT);
    for (int i = 0; i < 11; i++) {
        int nb = cdiv(LD[i].n, 1024);
        scan1_kernel<<<nb, 1024, 0, stream>>>(cnt + LD[i].ns, rp + LD[i].rpo, part, LD[i].n);
        scan2_kernel<<<1, 256, 0, stream>>>(part, nb);
        scan3_kernel<<<cdiv(LD[i].n, 256), 256, 0, stream>>>(rp + LD[i].rpo, part, LD[i].n, LD[i].E);
    }
    fill_zero_kernel<<<cdiv(NS_TOT, 256), 256, 0, stream>>>(cnt, NS_TOT);
    for (int i = 0; i < 11; i++)
        scatter_kernel<<<cdiv(LD[i].E, 256), 256, 0, stream>>>(LD[i].src, LD[i].dst, LD[i].E,
                                                               rp + LD[i].rpo, cnt + LD[i].ns,
                                                               col + LD[i].co);

    // ---- conv driver ----
    // window-local hs at hs+gbase*32; output into h+gbase*32 rows [row_lo, row_lo+n_pull)
    auto conv = [&](const float* in_rows, int F1, const float* in_stat, const float* W,
                    const float* b, int li, int gbase, int nwin, int row_lo, int n_pull) {
        float* hsw = hs + (size_t)gbase * DYNF;
        float* outw = h + (size_t)gbase * DYNF;
        const float* nrm = norms + LD[li].ns;
        if (F1 == 4)
            mm_scale_kernel<4, false><<<cdiv(nwin, 256), 256, 0, stream>>>(in_rows, nullptr, W, nrm, hsw, nwin);
        else
            mm_scale_kernel<32, true><<<cdiv(nwin, 256), 256, 0, stream>>>(in_rows, in_stat, W, nrm, hsw, nwin);
        pull_kernel<<<cdiv((long)n_pull * 8, 256), 256, 0, stream>>>(
            rp + LD[li].rpo, col + LD[li].co, hsw, nrm, b, outw, row_lo, n_pull);
    };

    auto inner = [&](int l) {
        int s = l * NLK;
        conv(h + (size_t)s * DYNF, 32, stat + (size_t)s * STATF, W_in, b_in,
             1 + l, s, NLK, 0, NLK);
    };
    auto fwd = [&](int l) {
        int s = l * NLK;
        conv(h + (size_t)s * DYNF, 32, stat + (size_t)s * STATF, W_f, b_f,
             5 + l, s, 2 * NLK, NLK, NLK);   // only rows [NL,2NL) of window
    };
    auto bwd = [&](int lm1) {
        int s = lm1 * NLK;
        conv(h + (size_t)s * DYNF, 32, stat + (size_t)s * STATF, W_b, b_b,
             8 + lm1, s, 2 * NLK, 0, NLK);   // only rows [0,NL) of window
    };

    // up conv: x -> h over all N
    conv(x, 4, nullptr, W_up, b_up, 0, 0, NN, 0, NN);

    for (int p = 0; p < 2; p++) {
        for (int l = 0; l < 4; l++) {
            inner(l);
            if (l < 3) fwd(l);
        }
        relu_kernel<<<cdiv((long)NN * DYNF, 256), 256, 0, stream>>>(h, NN * DYNF);
        for (int l = 3; l >= 1; l--) {
            bwd(l - 1);
            inner(l - 1);
        }
        relu_kernel<<<cdiv((long)NN * DYNF, 256), 256, 0, stream>>>(h, NN * DYNF);
    }

    init_out_kernel<<<1, 64, 0, stream>>>(out, lin_b);
    pool_kernel<<<NN / 256, 256, 0, stream>>>(h, gids, lin_W, out);
}